// Round 5
// baseline (1515.875 us; speedup 1.0000x reference)
//
#include <hip/hip_runtime.h>

// Problem constants: B=32, T=256, IN=64, D=128
// Outputs (fp32, concatenated): h_final[32,128] | y[32,256,128] | jacs[256,32,128,128] | dh_dWh[32,128,128,128]
// out offsets: 0, 4096, 1052672, 135270400  (total 202379264)

#define JACOFF 1052672L
#define DHWOFF 135270400L

typedef __attribute__((ext_vector_type(8))) short frag_ab;   // 8 bf16 (4 VGPRs)
typedef __attribute__((ext_vector_type(4))) float frag_cd;   // 4 fp32

__device__ __forceinline__ short f2bf(float f) {
    unsigned u = __builtin_bit_cast(unsigned, f);
    unsigned r = (u + 0x7fffu + ((u >> 16) & 1u)) >> 16;     // RNE
    return (short)r;
}

// agent-scope (device) relaxed atomic store/load: sc1 write-through/bypass so
// cross-XCD consumers see data at the coherence point without wbL2 fences.
__device__ __forceinline__ void st_agent(float* p, float v) {
    __hip_atomic_store(p, v, __ATOMIC_RELAXED, __HIP_MEMORY_SCOPE_AGENT);
}
__device__ __forceinline__ void st_agent_s16(short* p, short v) {
    __hip_atomic_store(p, v, __ATOMIC_RELAXED, __HIP_MEMORY_SCOPE_AGENT);
}
__device__ __forceinline__ void st_agent_u64(unsigned long long* p, unsigned long long v) {
    __hip_atomic_store(p, v, __ATOMIC_RELAXED, __HIP_MEMORY_SCOPE_AGENT);
}
__device__ __forceinline__ int ld_agent(const int* p) {
    return __hip_atomic_load(p, __ATOMIC_RELAXED, __HIP_MEMORY_SCOPE_AGENT);
}

// ---------- prep (blocks 0..127): transpose Wh, Wgate (+ block 0 zeroes sync); xw (blocks 128+) ----------
__global__ __launch_bounds__(256) void prep_xw_kernel(
    const float* __restrict__ Wh, const float* __restrict__ Wg,
    const float* __restrict__ x, const float* __restrict__ Wx,
    float* __restrict__ whT, float* __restrict__ wgT, float* __restrict__ xw,
    int* __restrict__ sync)
{
    int blk = blockIdx.x;
    int tid = threadIdx.x;
    if (blk < 128) {
        if (blk == 0 && tid < 64) sync[tid] = 0;     // zero handshake counters
        int idx = blk * 256 + tid;                   // 0..32767
        if (idx < 16384) {                           // WhT[i][k] = Wh[k][i]
            int k = idx >> 7, i = idx & 127;
            whT[i * 128 + k] = Wh[idx];
        } else {                                     // WgT[i][k] = Wgate[k][i]
            int r = idx - 16384;
            int k = r >> 7, i = r & 127;
            wgT[i * 128 + k] = Wg[r];
        }
        return;
    }
    // xw path: 2 (b,t) rows per block
    __shared__ float xs[2][64];
    int sub = tid >> 7;                              // 0/1
    int bt = (blk - 128) * 2 + sub;
    int i = tid & 127;
    if (i < 64) xs[sub][i] = x[bt * 64 + i];
    __syncthreads();
    float acc = 0.f;
#pragma unroll
    for (int m = 0; m < 64; ++m)
        acc += xs[sub][m] * Wx[m * 128 + i];         // Wx row: coalesced across i, L1-hot
    xw[bt * 128 + i] = acc;
}

// ---------- mega kernel: ticket-based roles ----------
// tickets 0..31   : scan (one per batch b) — publishes sync[b] = t+1 per step, 300 at end
// tickets 32..63  : pk (512 PT cols each) — publishes sync[33] += 1
// tickets 64..8255: jac tile jb = ticket-64 (rb = jb>>7, cb = jb&127); waits pk + sync[*] >= 4rb+4
// tickets 8256..  : dhdw unit = ticket-8256; waits sync[*] >= 300
// sync[0..31] per-batch scan progress; sync[33] pk-done count; sync[40] ticket counter.
__global__ __launch_bounds__(512, 4) void mega_kernel(
    const float* __restrict__ xw, const float* __restrict__ h0,
    const float* __restrict__ whT, const float* __restrict__ wgT,
    const float* __restrict__ Wgate, const float* __restrict__ Wh,
    float* __restrict__ out,
    short* __restrict__ Abf, float* __restrict__ wgv, float* __restrict__ wc,
    float* __restrict__ wdF, float* __restrict__ wuF, float* __restrict__ whF,
    short* __restrict__ PT, int* __restrict__ sync)
{
    union Sh {
        struct { short At[128 * 128]; short Bt[128 * 128]; } jac;   // 64 KB
        struct { float hbuf[2][128]; float abuf[128]; } scan;
        struct { float hs[128]; float dsh[128]; } dh;
    };
    __shared__ Sh sh;
    __shared__ int tkt_s;

    int tid = threadIdx.x;
    if (tid == 0) tkt_s = atomicAdd(&sync[40], 1);
    __syncthreads();
    const int ticket = tkt_s;

    if (ticket < 32) {
        // ================= scan role =================
        const int b = ticket;
        const int i = tid >> 2, qtr = tid & 3;
        float wh[32], wgc[32];
        {
            const float* whr = whT + i * 128 + qtr * 32;
            const float* wgr = wgT + i * 128 + qtr * 32;
#pragma unroll
            for (int k = 0; k < 32; k += 4) {
                float4 a4 = *(const float4*)(whr + k);
                wh[k] = a4.x; wh[k + 1] = a4.y; wh[k + 2] = a4.z; wh[k + 3] = a4.w;
                float4 b4 = *(const float4*)(wgr + k);
                wgc[k] = b4.x; wgc[k + 1] = b4.y; wgc[k + 2] = b4.z; wgc[k + 3] = b4.w;
            }
        }
        if (qtr == 0) sh.scan.hbuf[0][i] = h0[b * 128 + i];
        __syncthreads();

        const float inv_sqrt2 = 0.70710678118654752f;
        const float inv_sqrt2pi = 0.39894228040143268f;
        float xwv = xw[(b * 256 + 0) * 128 + i];

        for (int t = 0; t < 256; ++t) {
            int p = t & 1;
            int tn = (t < 255) ? t + 1 : 255;
            float xwn = xw[(b * 256 + tn) * 128 + i];      // prefetch next step

            float s0 = 0.f, s1 = 0.f, s2 = 0.f, s3 = 0.f;
            const float* hb = &sh.scan.hbuf[p][qtr * 32];
#pragma unroll
            for (int k = 0; k < 32; k += 4) {
                float4 h4 = *(const float4*)(hb + k);
                s0 += h4.x * wh[k];
                s1 += h4.y * wh[k + 1];
                s2 += h4.z * wh[k + 2];
                s3 += h4.w * wh[k + 3];
            }
            float s = (s0 + s1) + (s2 + s3);
            s += __shfl_xor(s, 1);
            s += __shfl_xor(s, 2);
            float pre = xwv + s;

            float cdf = 0.5f * (1.0f + erff(pre * inv_sqrt2));
            float a = pre * cdf;
            float dval = cdf + pre * inv_sqrt2pi * expf(-0.5f * pre * pre);

            long tb = (long)(t * 32 + b) * 128 + i;
            if (qtr == 0) {
                st_agent_s16(&Abf[tb], f2bf(dval));
                sh.scan.abuf[i] = a;
            }
            __syncthreads();                               // (1) abuf visible

            float r0 = 0.f, r1 = 0.f, r2 = 0.f, r3 = 0.f;
            const float* ab = &sh.scan.abuf[qtr * 32];
#pragma unroll
            for (int k = 0; k < 32; k += 4) {
                float4 a4 = *(const float4*)(ab + k);
                r0 += a4.x * wgc[k];
                r1 += a4.y * wgc[k + 1];
                r2 += a4.z * wgc[k + 2];
                r3 += a4.w * wgc[k + 3];
            }
            float r = (r0 + r1) + (r2 + r3);
            r += __shfl_xor(r, 1);
            r += __shfl_xor(r, 2);
            float g = 1.0f / (1.0f + expf(-r));
            float hp = sh.scan.hbuf[p][i];
            float c = (hp - 1.0f) * g * (1.0f - g);
            float hn = g * hp + 1.0f - g;
            if (qtr == 0) {
                sh.scan.hbuf[p ^ 1][i] = hn;
                st_agent(&wgv[tb], g);
                st_agent(&wc[tb], c);
                out[4096 + (b * 256 + t) * 128 + i] = hn;  // y (no cross-read: plain)
            }
            xwv = xwn;
            __syncthreads();                               // (2) drains all stores (vmcnt 0)
            if (tid == 0)                                  // publish step t complete
                __hip_atomic_store(&sync[b], t + 1, __ATOMIC_RELAXED, __HIP_MEMORY_SCOPE_AGENT);
        }

        float hfin = sh.scan.hbuf[0][i];
        if (qtr == 0) {
            out[b * 128 + i] = hfin;                       // h_final
            st_agent(&whF[b * 128 + i], hfin);
        }
        // extra evaluation at (x_last, h_final) for dh_dWh
        {
            float s0 = 0.f, s1 = 0.f, s2 = 0.f, s3 = 0.f;
            const float* hb = &sh.scan.hbuf[0][qtr * 32];
#pragma unroll
            for (int k = 0; k < 32; k += 4) {
                float4 h4 = *(const float4*)(hb + k);
                s0 += h4.x * wh[k];
                s1 += h4.y * wh[k + 1];
                s2 += h4.z * wh[k + 2];
                s3 += h4.w * wh[k + 3];
            }
            float s = (s0 + s1) + (s2 + s3);
            s += __shfl_xor(s, 1);
            s += __shfl_xor(s, 2);
            float pre = xwv + s;                           // xwv == xw[b, 255]
            float cdf = 0.5f * (1.0f + erff(pre * inv_sqrt2));
            float a = pre * cdf;
            float dval = cdf + pre * inv_sqrt2pi * expf(-0.5f * pre * pre);
            if (qtr == 0) {
                st_agent(&wdF[b * 128 + i], dval);
                sh.scan.abuf[i] = a;
            }
            __syncthreads();
            float r0 = 0.f, r1 = 0.f, r2 = 0.f, r3 = 0.f;
            const float* ab = &sh.scan.abuf[qtr * 32];
#pragma unroll
            for (int k = 0; k < 32; k += 4) {
                float4 a4 = *(const float4*)(ab + k);
                r0 += a4.x * wgc[k];
                r1 += a4.y * wgc[k + 1];
                r2 += a4.z * wgc[k + 2];
                r3 += a4.w * wgc[k + 3];
            }
            float r = (r0 + r1) + (r2 + r3);
            r += __shfl_xor(r, 1);
            r += __shfl_xor(r, 2);
            float g = 1.0f / (1.0f + expf(-r));
            if (qtr == 0) st_agent(&wuF[b * 128 + i], (hfin - 1.0f) * g * (1.0f - g));
        }
        __syncthreads();                                   // drain final stores
        if (tid == 0)
            __hip_atomic_store(&sync[b], 300, __ATOMIC_RELAXED, __HIP_MEMORY_SCOPE_AGENT);
        return;
    }

    if (ticket < 64) {
        // ================= pk role: 512 PT cols =================
        int pkb = ticket - 32;
#pragma unroll 1
        for (int pass = 0; pass < 16; ++pass) {
            int c = pkb * 512 + pass * 32 + (tid >> 4);
            int k0 = (tid & 15) * 8;
            int i = c >> 7, j = c & 127;
            short v[8];
#pragma unroll
            for (int m = 0; m < 8; ++m) {
                float wg = Wgate[(k0 + m) * 128 + i];
                float wh = Wh[j * 128 + k0 + m];
                v[m] = f2bf(wg * wh);
            }
            unsigned long long* dst = (unsigned long long*)(PT + (long)c * 128 + k0);
            unsigned long long* sv = (unsigned long long*)v;
            st_agent_u64(dst, sv[0]);
            st_agent_u64(dst + 1, sv[1]);
        }
        __syncthreads();                                   // drain pk stores
        if (tid == 0) atomicAdd(&sync[33], 1);
        return;
    }

    if (ticket < 64 + 8192) {
        // ================= jac role =================
        int jb = ticket - 64;
        int rb = jb >> 7, cb = jb & 127;

        if (tid == 0) {
            while (ld_agent(&sync[33]) < 32) __builtin_amdgcn_s_sleep(2);
            int thr = 4 * rb + 4;
            for (int b = 0; b < 32; ++b)
                while (ld_agent(&sync[b]) < thr) __builtin_amdgcn_s_sleep(2);
        }
        __syncthreads();                                   // all threads see "data ready"

        const short* Ag = Abf + (long)rb * (128 * 128);
        const short* Bg = PT + (long)cb * (128 * 128);
        // stage tiles: 2048 16B chunks, XOR-swizzled via per-lane global source
#pragma unroll
        for (int e = 0; e < 4; ++e) {
            int q = e * 512 + tid;
            int r = q >> 4;
            int s = q & 15;
            int ko = s ^ (r & 15);
            const short* srcA = Ag + r * 128 + ko * 8;
            const short* srcB = Bg + r * 128 + ko * 8;
            __builtin_amdgcn_global_load_lds(
                (const __attribute__((address_space(1))) void*)srcA,
                (__attribute__((address_space(3))) void*)(sh.jac.At + q * 8), 16, 0, 0);
            __builtin_amdgcn_global_load_lds(
                (const __attribute__((address_space(1))) void*)srcB,
                (__attribute__((address_space(3))) void*)(sh.jac.Bt + q * 8), 16, 0, 0);
        }

        int w = tid >> 6;            // wave 0..7
        int lane = tid & 63;
        int wr = w & 1;              // row half (64)
        int wcol = w >> 1;           // col quarter (32)
        int lrow = lane & 15;
        int quad = lane >> 4;

        // prefetch epilogue gathers (post-flag first touch; hidden under MFMA)
        long rowbase = (long)rb * 128;
        float ci[4][4], gi[4][4];
#pragma unroll
        for (int p = 0; p < 4; ++p) {
            int trow0 = wr * 64 + p * 16 + quad * 4;
#pragma unroll
            for (int reg = 0; reg < 4; ++reg) {
                long row = rowbase + trow0 + reg;
                ci[p][reg] = wc[row * 128 + cb];
                gi[p][reg] = wgv[row * 128 + cb];
            }
        }
        __syncthreads();                                   // waits LDS-DMA (vmcnt)

        frag_cd acc[4][2];
#pragma unroll
        for (int p = 0; p < 4; ++p)
#pragma unroll
            for (int q2 = 0; q2 < 2; ++q2) {
                acc[p][q2][0] = 0.f; acc[p][q2][1] = 0.f;
                acc[p][q2][2] = 0.f; acc[p][q2][3] = 0.f;
            }

#pragma unroll
        for (int kk = 0; kk < 4; ++kk) {                   // k-chunks of 32
            int ko = kk * 4 + quad;
            frag_ab af[4], bf[2];
#pragma unroll
            for (int p = 0; p < 4; ++p) {
                int r = wr * 64 + p * 16 + lrow;
                int chunk = r * 16 + (ko ^ (r & 15));
                af[p] = *(const frag_ab*)&sh.jac.At[chunk * 8];
            }
#pragma unroll
            for (int q2 = 0; q2 < 2; ++q2) {
                int n = wcol * 32 + q2 * 16 + lrow;
                int chunk = n * 16 + (ko ^ (n & 15));
                bf[q2] = *(const frag_ab*)&sh.jac.Bt[chunk * 8];
            }
#pragma unroll
            for (int p = 0; p < 4; ++p)
#pragma unroll
                for (int q2 = 0; q2 < 2; ++q2)
                    acc[p][q2] = __builtin_amdgcn_mfma_f32_16x16x32_bf16(af[p], bf[q2], acc[p][q2], 0, 0, 0);
        }

        // epilogue: C/D layout col = lane&15, row = quad*4 + reg
#pragma unroll
        for (int p = 0; p < 4; ++p) {
            int trow0 = wr * 64 + p * 16 + quad * 4;
#pragma unroll
            for (int reg = 0; reg < 4; ++reg) {
                long row = rowbase + trow0 + reg;
                float* orow = out + JACOFF + row * 16384 + (long)cb * 128;
#pragma unroll
                for (int q2 = 0; q2 < 2; ++q2) {
                    int tcol = wcol * 32 + q2 * 16 + lrow;
                    float v = ci[p][reg] * acc[p][q2][reg];
                    if (tcol == cb) v += gi[p][reg];
                    orow[tcol] = v;
                }
            }
        }
        return;
    }

    // ================= dhdw role =================
    {
        int u = ticket - (64 + 8192);                      // 0..4095 = b*128 + i
        int b = u >> 7, i = u & 127;
        if (tid == 0) {
            for (int bb = 0; bb < 32; ++bb)
                while (ld_agent(&sync[bb]) < 300) __builtin_amdgcn_s_sleep(2);
        }
        __syncthreads();
        if (tid < 128) {
            sh.dh.hs[tid] = whF[b * 128 + tid];
            sh.dh.dsh[tid] = wdF[b * 128 + tid];
        }
        __syncthreads();
        float uv = wuF[b * 128 + i];
        int q0 = (tid & 31) * 4, p0 = (tid >> 5) * 8;
        float w0 = uv * sh.dh.dsh[q0 + 0] * Wgate[(q0 + 0) * 128 + i];
        float w1 = uv * sh.dh.dsh[q0 + 1] * Wgate[(q0 + 1) * 128 + i];
        float w2 = uv * sh.dh.dsh[q0 + 2] * Wgate[(q0 + 2) * 128 + i];
        float w3 = uv * sh.dh.dsh[q0 + 3] * Wgate[(q0 + 3) * 128 + i];
        float* dst = out + DHWOFF + (long)u * 16384;
#pragma unroll
        for (int pp = 0; pp < 8; ++pp) {
            float hp = sh.dh.hs[p0 + pp];
            *(float4*)(dst + (p0 + pp) * 128 + q0) = make_float4(hp * w0, hp * w1, hp * w2, hp * w3);
        }
    }
}

extern "C" void kernel_launch(void* const* d_in, const int* in_sizes, int n_in,
                              void* d_out, int out_size, void* d_ws, size_t ws_size,
                              hipStream_t stream)
{
    (void)in_sizes; (void)n_in; (void)out_size; (void)ws_size;
    const float* x     = (const float*)d_in[0];
    const float* h0    = (const float*)d_in[1];
    const float* Wx    = (const float*)d_in[2];
    const float* Wgate = (const float*)d_in[3];
    const float* Wh    = (const float*)d_in[4];
    float* out = (float*)d_out;
    float* ws  = (float*)d_ws;

    // workspace layout (floats), ~19 MB total
    float* xw  = ws;                         // 1048576  [b][t][i]
    float* whT = ws + 1048576;               // 16384
    float* wgT = ws + 1064960;               // 16384
    float* wgv = ws + 1081344;               // 1048576  [t*32+b][i]
    float* wc  = ws + 2129920;               // 1048576
    float* wdF = ws + 3178496;               // 4096
    float* wuF = ws + 3182592;               // 4096
    float* whF = ws + 3186688;               // 4096
    short* Abf = (short*)(ws + 3190784);     // 1048576 bf16 (524288 floats) [t*32+b][k]
    short* PT  = (short*)(ws + 3715072);     // 2097152 bf16 (1048576 floats) [col][k]
    int*   syn = (int*)(ws + 4763648);       // 64 ints handshake area

    prep_xw_kernel<<<4224, 256, 0, stream>>>(Wh, Wgate, x, Wx, whT, wgT, xw, syn);
    mega_kernel<<<12352, 512, 0, stream>>>(xw, h0, whT, wgT, Wgate, Wh, out,
                                           Abf, wgv, wc, wdF, wuF, whF, PT, syn);
}